// Round 10
// baseline (285.257 us; speedup 1.0000x reference)
//
#include <hip/hip_runtime.h>

#define B_  4
#define C_  64
#define H_  256
#define W_  256
#define HW_ 65536
#define NPIX_ (B_*HW_)        /* 262144 */
#define NELEM_ (B_*C_*HW_)    /* 16777216 */

#define OMS 200     /* bf16 om row stride in LDS (400B: 16B-aligned) */
#define TS  72      /* bf16 sval row stride in LDS (144B: 16B-aligned) */

typedef __attribute__((ext_vector_type(8))) short short8;
typedef __attribute__((ext_vector_type(4))) float floatx4;
typedef __attribute__((ext_vector_type(2))) __fp16 h2f;   // matches cvt_pkrtz return

static __device__ __forceinline__ unsigned short f2bf(float f){
  unsigned u = __float_as_uint(f);
  u += 0x7fff + ((u >> 16) & 1);          // RNE
  return (unsigned short)(u >> 16);
}
static __device__ __forceinline__ float bf2f(unsigned short s){
  return __uint_as_float(((unsigned)s) << 16);
}
static __device__ __forceinline__ unsigned pack2(float a, float b){
  return (unsigned)f2bf(a) | ((unsigned)f2bf(b) << 16);
}

// ---------------- K0: weights -> bf16, zero stats ---------------------------
__global__ __launch_bounds__(256) void k_setup(
    const float* __restrict__ pw, const float* __restrict__ w2,
    unsigned short* __restrict__ wB, float* __restrict__ stats0)
{
  int tid = threadIdx.x;
  if (blockIdx.x < 64){
    int i = blockIdx.x*256 + tid;
    wB[i] = f2bf(i < 12288 ? pw[i] : w2[i - 12288]);
  } else {
#pragma unroll
    for (int k = 0; k < 16; ++k) stats0[k*256 + tid] = 0.f;
  }
}

// ---------------- K1: MEGA-FUSED dwconv -> GEMM1 -> sample -> GEMM2 ---------
// Phase 0 computes, per thread, EXACTLY the 16 dwconv channel-values its own
// MFMA A-fragment needs (pixel bid*64+wv*16+mrow, channels kb*32+q*8..+7)
// straight into bfrag registers: no t LDS tile, no phase0->A barrier.
// LDS = OM only (25600 B; T for phase C + red overlay the dead OM region)
// -> 5+ blocks/CU at launch_bounds(256,5).
__global__ __launch_bounds__(256, 5) void k_fuse(
    const float* __restrict__ x,
    const float* __restrict__ dwW,
    const unsigned short* __restrict__ pwB,
    const unsigned short* __restrict__ w2B,
    unsigned short* __restrict__ outB,
    float* __restrict__ gsumS,
    float* __restrict__ gsqS)
{
  __shared__ __align__(16) char lds[25600];
  unsigned short* OM = (unsigned short*)lds;        // 64 x OMS bf16 (phases A..B)
  unsigned short* T  = (unsigned short*)lds;        // 64 x TS bf16 (phase C, overlays dead OM)
  float* red1 = (float*)(lds + 9216);               // epilogue (overlays dead OM)
  float* red2 = (float*)(lds + 10240);

  int tid = threadIdx.x;
  int bid = ((blockIdx.x & 7) << 9) + (blockIdx.x >> 3);   // XCD-contiguous
  int b    = bid >> 10;
  int tile = bid & 1023;
  int h    = tile >> 2;
  int w0   = (tile & 3) << 6;
  int p  = tid & 63;            // block-local pixel (phase B / phase 0-write mapping)
  int cg = tid >> 6;

  int wv = tid >> 6, lane = tid & 63;
  int mrow = lane & 15, q = lane >> 4;
  int pxw = bid*64 + wv*16;     // wave's pixel base (16 px per wave)

  // ======== phase 0: dwconv -> bfrag registers (per-thread fragment) =======
  short8 bfrag[2];
  {
    int col = w0 + wv*16 + mrow;          // this thread's fragment pixel column
    int rm = (h > 0   ? h-1 : 0) << 8;
    int r0 = h << 8;
    int rp = (h < 255 ? h+1 : 255) << 8;
    float vm = (h > 0)   ? 1.f : 0.f;
    float vp = (h < 255) ? 1.f : 0.f;
    int st = min(max(col - 1, 0), 253);
    int d  = col - st;                    // 0: col==0, 2: col==255, else 1
    bool d0 = (d == 0), d2 = (d == 2);
    int om = (rm + st) << 2;
    int oc = (r0 + st) << 2;
    int op = (rp + st) << 2;

    const char* xbase = (const char*)(x + ((size_t)(b*C_) << 16));

#pragma unroll
    for (int kb = 0; kb < 2; ++kb){
      union { unsigned u[4]; short8 s8; } cv;
#pragma unroll
      for (int sb = 0; sb < 2; ++sb){     // 2 sub-batches of 4 channels
        float3 v[4][3];
        float3 wr[4][3];
#pragma unroll
        for (int j = 0; j < 4; ++j){
          int c = kb*32 + q*8 + sb*4 + j;
          const char* pl = xbase + (((size_t)c) << 18);
          __builtin_memcpy(&v[j][0], pl + om, 12);
          __builtin_memcpy(&v[j][1], pl + oc, 12);
          __builtin_memcpy(&v[j][2], pl + op, 12);
          const float* wp = dwW + c*9;
          __builtin_memcpy(&wr[j][0], wp,     12);
          __builtin_memcpy(&wr[j][1], wp + 3, 12);
          __builtin_memcpy(&wr[j][2], wp + 6, 12);
        }
        __builtin_amdgcn_sched_barrier(0);   // loads may not sink past this
        unsigned pkv[2];
#pragma unroll
        for (int j = 0; j < 4; ++j){
          float acc = 0.f;
#pragma unroll
          for (int r = 0; r < 3; ++r){
            float3 f = v[j][r];
            float3 wf = wr[j][r];
            float xl = d0 ? 0.f : (d2 ? f.y : f.x);
            float xc = d0 ? f.x : (d2 ? f.z : f.y);
            float xr = d2 ? 0.f : (d0 ? f.y : f.z);
            float rowscale = (r == 0) ? vm : (r == 2 ? vp : 1.f);
            acc += rowscale * (wf.x*xl + wf.y*xc + wf.z*xr);
          }
          unsigned short bv = f2bf(acc);
          if (j & 1) pkv[j>>1] |= ((unsigned)bv << 16);
          else       pkv[j>>1]  = (unsigned)bv;
        }
        cv.u[sb*2]     = pkv[0];
        cv.u[sb*2 + 1] = pkv[1];
      }
      bfrag[kb] = cv.s8;
    }
  }
  // no barrier: bfrag is register-private

  // ======== phase A: GEMM1  om[px][ch] = sum_c t[px][c]*pw[ch][c] ========
  floatx4 acc[12];
#pragma unroll
  for (int mt = 0; mt < 12; ++mt) acc[mt] = (floatx4){0.f,0.f,0.f,0.f};
#pragma unroll
  for (int kb = 0; kb < 2; ++kb)
#pragma unroll
    for (int mt = 0; mt < 12; ++mt){
      short8 af = *(const short8*)(pwB + (mt*16 + mrow)*64 + kb*32 + q*8);
      acc[mt] = __builtin_amdgcn_mfma_f32_16x16x32_bf16(af, bfrag[kb], acc[mt], 0, 0, 0);
    }

  {
    int omrow = (wv*16 + mrow)*OMS;
#pragma unroll
    for (int mt = 0; mt < 12; ++mt){
      uint2 u; u.x = pack2(acc[mt][0], acc[mt][1]); u.y = pack2(acc[mt][2], acc[mt][3]);
      *(uint2*)(OM + omrow + mt*16 + q*4) = u;
    }
  }
  __syncthreads();

  // ======== phase B: deformable bilinear sampling, fp32 gathers from x =====
  unsigned pk[8];
  {
    float hf = (float)h, wf = (float)(w0 + p);   // this thread's pixel
    const char* xbyte = (const char*)(x + ((size_t)(b*C_ + cg*16) << 16));

#pragma unroll
    for (int half = 0; half < 2; ++half){
      const uint4* ob = (const uint4*)(OM + p*OMS + cg*32 + half*16);
      uint4 oA = ob[0], oB = ob[1];
      uint4 mv = *(const uint4*)(OM + p*OMS + 128 + cg*16 + half*8);
      unsigned pr[8] = {oA.x,oA.y,oA.z,oA.w, oB.x,oB.y,oB.z,oB.w};
      unsigned md4[4] = {mv.x,mv.y,mv.z,mv.w};

      h2f wrv[8], wcv[8];
      unsigned ad0[8], ad1[8];

      // ---- stage: weights + addresses ----
#pragma unroll
      for (int i = 0; i < 8; ++i){
        unsigned pair = pr[i];
        float oy = __uint_as_float(pair << 16);
        float ox = __uint_as_float(pair & 0xffff0000u);
        float mm = __uint_as_float((i & 1) ? (md4[i>>1] & 0xffff0000u)
                                           : (md4[i>>1] << 16));
        float mod = 2.f * __builtin_amdgcn_rcpf(1.f + __expf(-mm));
        oy = fminf(fmaxf(oy, -64.f), 64.f);
        ox = fminf(fmaxf(ox, -64.f), 64.f);
        float sy = hf + oy, sx = wf + ox;
        float y0f = floorf(sy), x0f = floorf(sx);
        float wy = sy - y0f, wxr = sx - x0f;
        int y0 = (int)y0f, x0 = (int)x0f;
        int yc0 = min(max(y0,     0), 255);
        int yc1 = min(max(y0 + 1, 0), 255);    // clamp AFTER increment
        int xc  = min(max(x0, 0), 254);        // pair start (always in-plane)
        bool y0v = ((unsigned)y0       < 256u);
        bool y1v = ((unsigned)(y0 + 1) < 256u);
        bool x0v = ((unsigned)x0       < 256u);
        bool x1v = ((unsigned)(x0 + 1) < 256u);
        bool x0lo = (x0 == xc);
        float r0 = y0v ? (1.f - wy) * mod : 0.f;
        float r1 = y1v ? wy * mod : 0.f;
        float c0w = x0v ? (1.f - wxr) : 0.f;
        float c1w = x1v ? wxr : 0.f;
        float cA = x0lo ? c0w : c1w;           // weight on value at xc
        float cB = x0lo ? c1w : c0w;           // weight on value at xc+1
        wrv[i] = __builtin_amdgcn_cvt_pkrtz(r0, r1);
        wcv[i] = __builtin_amdgcn_cvt_pkrtz(cA, cB);
        unsigned cb = ((unsigned)(half*8 + i)) << 18;   // fp32 plane = 256 KB
        ad0[i] = cb + ((unsigned)yc0 << 10) + ((unsigned)xc << 2);
        ad1[i] = cb + ((unsigned)yc1 << 10) + ((unsigned)xc << 2);
      }

      // ---- issue all 16 8-byte gathers ----
      float2 pu0[8], pu1[8];
#pragma unroll
      for (int i = 0; i < 8; ++i){
        __builtin_memcpy(&pu0[i], xbyte + ad0[i], 8);   // (y0 , x: xc, xc+1)
        __builtin_memcpy(&pu1[i], xbyte + ad1[i], 8);   // (y0+1, same)
      }
      __builtin_amdgcn_sched_barrier(0);   // loads may not sink below here

      // ---- consume ----
#pragma unroll
      for (int i = 0; i < 8; ++i){
        int ci = half*8 + i;
        float cA = (float)wcv[i].x, cB = (float)wcv[i].y;
        float r0 = (float)wrv[i].x, r1 = (float)wrv[i].y;
        float sres = r0*(cA*pu0[i].x + cB*pu0[i].y)
                   + r1*(cA*pu1[i].x + cB*pu1[i].y);
        unsigned short bv = f2bf(sres);
        if (ci & 1) pk[ci>>1] |= ((unsigned)bv << 16);
        else        pk[ci>>1]  = (unsigned)bv;
      }
    }
  }
  __syncthreads();              // all OM reads done; T may overlay OM now

  {
    uint4 u0; u0.x = pk[0]; u0.y = pk[1]; u0.z = pk[2]; u0.w = pk[3];
    uint4 u1; u1.x = pk[4]; u1.y = pk[5]; u1.z = pk[6]; u1.w = pk[7];
    *(uint4*)(T + p*TS + cg*16)     = u0;
    *(uint4*)(T + p*TS + cg*16 + 8) = u1;
  }
  __syncthreads();

  // ======== phase C: GEMM2  out[px][och] = sum_c sval[px][c]*w2[och][c] ====
  short8 a2[2];
#pragma unroll
  for (int kb = 0; kb < 2; ++kb)
    a2[kb] = *(const short8*)(T + (wv*16 + mrow)*TS + kb*32 + q*8);

  floatx4 acc2[4];
#pragma unroll
  for (int nt = 0; nt < 4; ++nt) acc2[nt] = (floatx4){0.f,0.f,0.f,0.f};
#pragma unroll
  for (int kb = 0; kb < 2; ++kb)
#pragma unroll
    for (int nt = 0; nt < 4; ++nt){
      short8 bf = *(const short8*)(w2B + (nt*16 + mrow)*64 + kb*32 + q*8);
      acc2[nt] = __builtin_amdgcn_mfma_f32_16x16x32_bf16(a2[kb], bf, acc2[nt], 0, 0, 0);
    }

  int bb  = pxw >> 16;
  int hw0 = pxw & (HW_-1);
#pragma unroll
  for (int nt = 0; nt < 4; ++nt){
    int och = nt*16 + mrow;
    float a0 = acc2[nt][0], a1 = acc2[nt][1], a2v = acc2[nt][2], a3 = acc2[nt][3];
    uint2 u; u.x = pack2(a0, a1); u.y = pack2(a2v, a3);
    *(uint2*)(outB + ((size_t)(bb*C_ + och) << 16) + hw0 + q*4) = u;
    float s1 = a0 + a1 + a2v + a3;
    float s2 = a0*a0 + a1*a1 + a2v*a2v + a3*a3;
    s1 += __shfl_xor(s1, 16, 64);  s2 += __shfl_xor(s2, 16, 64);
    s1 += __shfl_xor(s1, 32, 64);  s2 += __shfl_xor(s2, 32, 64);
    if (q == 0){ red1[wv*64 + och] = s1; red2[wv*64 + och] = s2; }
  }
  __syncthreads();
  if (tid < 64){
    float t1 = red1[tid] + red1[64+tid] + red1[128+tid] + red1[192+tid];
    float t2 = red2[tid] + red2[64+tid] + red2[128+tid] + red2[192+tid];
    int slot = blockIdx.x & 31;
    atomicAdd(&gsumS[slot*64 + tid], t1);
    atomicAdd(&gsqS[slot*64 + tid], t2);
  }
}

// GELU: tanh-form collapses to a * sigmoid(2k(a + 0.044715 a^3)), k=sqrt(2/pi).
static __device__ __forceinline__ float gelu1(float a){
  float u = a*a;
  float wv = fmaf(u*a, -0.0713548162726f, a * -1.5957691216f);  // -2k(a+c a^3)
  return a * __builtin_amdgcn_rcpf(1.f + __expf(wv));
}

// ---------------- K5: BN finalize (wave-cooperative) + apply + GELU ---------
// 2048 blocks, grid-stride 4 iters. Chunk = 1024 uint4 < one channel period
// (8192 uint4) -> och block-uniform. Stats reduced once per wave: lane<32
// loads gsum slot, lane>=32 gsq slot, 5 xor-shuffles, broadcast. Replaces 64
// serial broadcast loads PER THREAD (134M VMEM insts) with 1 per lane.
__global__ __launch_bounds__(256) void k_bn_gelu(
    const uint4* __restrict__ outB4,   // 8 bf16
    const float* __restrict__ gsumS,
    const float* __restrict__ gsqS,
    const float* __restrict__ gamma,
    const float* __restrict__ beta,
    float4* __restrict__ y4)
{
  int tid = threadIdx.x;
  int och = (blockIdx.x >> 3) & 63;               // block-uniform
  int l = tid & 63;
  float part = (l < 32) ? gsumS[l*64 + och] : gsqS[(l-32)*64 + och];
  part += __shfl_xor(part, 1, 64);
  part += __shfl_xor(part, 2, 64);
  part += __shfl_xor(part, 4, 64);
  part += __shfl_xor(part, 8, 64);
  part += __shfl_xor(part, 16, 64);
  float s1 = __shfl(part, 0, 64);
  float s2 = __shfl(part, 32, 64);
  float mean = s1 * (1.f/(float)NPIX_);
  float var  = s2 * (1.f/(float)NPIX_) - mean*mean;   // biased, matches jnp.var
  float sc = gamma[och] * rsqrtf(var + 1e-5f);
  float sh = beta[och] - mean*sc;

#pragma unroll
  for (int it = 0; it < 4; ++it){
    int i = blockIdx.x*1024 + it*256 + tid;       // over NELEM_/8
    uint4 u = outB4[i];
    float e[8];
    e[0] = bf2f((unsigned short)(u.x & 0xffffu)); e[1] = bf2f((unsigned short)(u.x >> 16));
    e[2] = bf2f((unsigned short)(u.y & 0xffffu)); e[3] = bf2f((unsigned short)(u.y >> 16));
    e[4] = bf2f((unsigned short)(u.z & 0xffffu)); e[5] = bf2f((unsigned short)(u.z >> 16));
    e[6] = bf2f((unsigned short)(u.w & 0xffffu)); e[7] = bf2f((unsigned short)(u.w >> 16));
    float4 o0, o1;
    o0.x = gelu1(fmaf(e[0], sc, sh));
    o0.y = gelu1(fmaf(e[1], sc, sh));
    o0.z = gelu1(fmaf(e[2], sc, sh));
    o0.w = gelu1(fmaf(e[3], sc, sh));
    o1.x = gelu1(fmaf(e[4], sc, sh));
    o1.y = gelu1(fmaf(e[5], sc, sh));
    o1.z = gelu1(fmaf(e[6], sc, sh));
    o1.w = gelu1(fmaf(e[7], sc, sh));
    y4[2*i]   = o0;
    y4[2*i+1] = o1;
  }
}

extern "C" void kernel_launch(void* const* d_in, const int* in_sizes, int n_in,
                              void* d_out, int out_size, void* d_ws, size_t ws_size,
                              hipStream_t stream)
{
  (void)in_sizes; (void)n_in; (void)out_size; (void)ws_size;
  const float* x     = (const float*)d_in[0];
  const float* dw    = (const float*)d_in[1];
  const float* pw    = (const float*)d_in[2];
  const float* w2    = (const float*)d_in[3];
  /* d_in[4] = bias: cancels exactly in BN (mean-subtracted), unused */
  const float* gamma = (const float*)d_in[5];
  const float* beta  = (const float*)d_in[6];

  // ws layout:
  //   [0,         33554432)  outB  bf16 conv2 out, och-major
  //   [33554432,  33570816)  stats (gsumS 8K, gsqS 8K)
  //   [33570816,  33603584)  wB    bf16 weights (pw 24K, w2 8K)
  char* ws = (char*)d_ws;
  unsigned short* outB  = (unsigned short*)ws;
  float*          stats = (float*)(ws + 33554432);
  float* gsumS = stats;                 // 32 slots x 64
  float* gsqS  = stats + 2048;
  unsigned short* wB  = (unsigned short*)(ws + 33570816);
  unsigned short* pwB = wB;
  unsigned short* w2B = wB + 12288;

  k_setup   <<<65, 256, 0, stream>>>(pw, w2, wB, stats);
  k_fuse    <<<NPIX_/64, 256, 0, stream>>>(x, dw, pwB, w2B, outB, gsumS, gsqS);
  k_bn_gelu <<<2048, 256, 0, stream>>>((const uint4*)outB, gsumS, gsqS,
                                       gamma, beta, (float4*)d_out);
}